// Round 15
// baseline (307.586 us; speedup 1.0000x reference)
//
#include <hip/hip_runtime.h>
#include <stdint.h>
#include <math.h>

typedef __bf16 bf16;
typedef float f32x4 __attribute__((ext_vector_type(4)));
typedef long  lx2  __attribute__((ext_vector_type(2)));

#define B_DIM 8192
#define K_DIM 4096
#define N_DIM 4096
#define MEM_H 1048576
#define HMOD  1047552   // MEM_H - 32*32
#define NT2   32        // K-steps of 128

// ---------------- host-side numpy legacy RNG replication ----------------
static void mt_randint3(uint32_t seed, long long R[3]) {
  uint32_t mt[624];
  mt[0] = seed;
  for (int i = 1; i < 624; i++)
    mt[i] = 1812433253u * (mt[i - 1] ^ (mt[i - 1] >> 30)) + (uint32_t)i;
  int pos = 624;
  auto next32 = [&]() -> uint32_t {
    if (pos >= 624) {
      for (int i = 0; i < 624; i++) {
        uint32_t y = (mt[i] & 0x80000000u) | (mt[(i + 1) % 624] & 0x7fffffffu);
        uint32_t v = mt[(i + 397) % 624] ^ (y >> 1);
        if (y & 1u) v ^= 0x9908b0dfu;
        mt[i] = v;
      }
      pos = 0;
    }
    uint32_t y = mt[pos++];
    y ^= y >> 11;
    y ^= (y << 7) & 0x9d2c5680u;
    y ^= (y << 15) & 0xefc60000u;
    y ^= y >> 18;
    return y;
  };
  for (int j = 0; j < 3; j++) {
    uint32_t v;
    do { v = next32() & 0x7fffffffu; } while (v > 0x7ffffffdu);
    R[j] = 1LL + (long long)v;
  }
}

// ---------------- f32 -> OCP e4m3fn, RTN-even, with subnormals ----------
__device__ __forceinline__ uint32_t f2e4m3(float f) {
  uint32_t u = __float_as_uint(f);
  uint32_t s = (u >> 24) & 0x80u;
  float a = fabsf(f);
  uint32_t b;
  if (a < 0.015625f) {
    b = (uint32_t)(int)rintf(a * 512.0f);        // 0..8 ; 8 == 2^-6 normal
  } else {
    uint32_t au = __float_as_uint(a);
    au += 0x7FFFFu + ((au >> 20) & 1u);          // round mantissa to 3 bits
    int E = (int)(au >> 23) - 127;
    if (E > 8) b = 0x7Eu;                        // saturate to 448
    else b = (uint32_t)(((E + 7) << 3) | ((au >> 20) & 7u));
  }
  return b | s;
}

// -------- fused pre-pass: quantize x AND build W^T, PACKED layout -------
// Packed 64B k-group: 16B chunk c = [k 8c..8c+7 | k 32+8c..32+8c+7].
__global__ void k_prep(const float* __restrict__ x, uint8_t* __restrict__ xq,
                       const float* __restrict__ hw, uint8_t* __restrict__ wq,
                       long long R1, long long R2, long long R3) {
  if (blockIdx.x < 8192) {
    int id = blockIdx.x * 256 + threadIdx.x;     // one packed 16B chunk
    int row = id >> 8, q = id & 255;
    int g = q >> 2, c = q & 3;
    const float* base = x + (size_t)row * 4096 + g * 64 + c * 8;
    f32x4 v0 = *(const f32x4*)(base);
    f32x4 v1 = *(const f32x4*)(base + 4);
    f32x4 v2 = *(const f32x4*)(base + 32);
    f32x4 v3 = *(const f32x4*)(base + 36);
    uint32_t r0 = f2e4m3(v0[0]) | (f2e4m3(v0[1]) << 8) |
                  (f2e4m3(v0[2]) << 16) | (f2e4m3(v0[3]) << 24);
    uint32_t r1 = f2e4m3(v1[0]) | (f2e4m3(v1[1]) << 8) |
                  (f2e4m3(v1[2]) << 16) | (f2e4m3(v1[3]) << 24);
    uint32_t r2 = f2e4m3(v2[0]) | (f2e4m3(v2[1]) << 8) |
                  (f2e4m3(v2[2]) << 16) | (f2e4m3(v2[3]) << 24);
    uint32_t r3 = f2e4m3(v3[0]) | (f2e4m3(v3[1]) << 8) |
                  (f2e4m3(v3[2]) << 16) | (f2e4m3(v3[3]) << 24);
    ((uint4*)xq)[id] = make_uint4(r0, r1, r2, r3);
  } else {
    int tile = blockIdx.x - 8192;
    int kb = tile & 127, nb = tile >> 7;
    long long v = (long long)kb * R3 + (long long)nb * R2 + R1;
    int start = (int)((v % 2147483647LL) % (long long)HMOD);
    const float* src = hw + start;
    int t = threadIdx.x;
    int nl = t >> 3, k4 = t & 7;
    uint32_t b = 0;
#pragma unroll
    for (int j = 0; j < 4; j++)
      b |= f2e4m3(src[(k4 * 4 + j) * 32 + nl] * 64.0f) << (8 * j);
    size_t off = (size_t)(nb * 32 + nl) * 4096 + (kb >> 1) * 64 +
                 (k4 >> 1) * 16 + (kb & 1) * 8 + (k4 & 1) * 4;
    *(uint32_t*)(wq + off) = b;
  }
}

// ---- 256x256 fp8 GEMM: R14's 2-barrier K=128 skeleton, R13's MFMAs ------
// Per iter (K=128): 24 b128 reads, 128 fp8 16x16x32 MFMAs in 4 lgkm-gated
// clusters, 8 DMA stages, exactly 2 barriers:
//   BAR#1 after all waves' LGKM(0) -> both buffers' reads done chip-wide,
//   stages may overwrite; BAR#2 after VMC(0) -> all waves' DMA landed.
// (vmcnt is per-wave: counted wait must come BEFORE its barrier.)
__device__ __forceinline__ void gload_lds16(const void* g, void* l) {
  __builtin_amdgcn_global_load_lds(
      (const __attribute__((address_space(1))) void*)g,
      (__attribute__((address_space(3))) void*)l, 16, 0, 0);
}

#define SGB() __builtin_amdgcn_sched_barrier(0)
#define VMC(n)  do { SGB(); asm volatile("s_waitcnt vmcnt(" #n ")"); SGB(); } while (0)
#define LGKM(n) do { SGB(); asm volatile("s_waitcnt lgkmcnt(" #n ")"); SGB(); } while (0)
#define BAR() __builtin_amdgcn_s_barrier()
#define DSR128(dst, base, off) \
  asm volatile("ds_read_b128 %0, %1 offset:" off : "=&v"(dst) : "v"(base))

// accumulate one 64-k group pair into D: AV/BV are lx2 ([0]=ks0,[1]=ks1)
#define FMP(D, AV, BV) do {                                                    \
  D = __builtin_amdgcn_mfma_f32_16x16x32_fp8_fp8((AV)[0], (BV)[0], D, 0, 0, 0);\
  D = __builtin_amdgcn_mfma_f32_16x16x32_fp8_fp8((AV)[1], (BV)[1], D, 0, 0, 0);\
} while (0)

__global__ __launch_bounds__(512, 2) void k_gemm(const uint8_t* __restrict__ Aq,
                                                 const uint8_t* __restrict__ Bq,
                                                 float* __restrict__ partial) {
  // [buf = k-group parity][op 0=A 1=B][half][8 units x 1KB] : 64 KiB
  __shared__ uint8_t smq[2][2][2][128 * 64];
  int bid = blockIdx.x;
  int swz = (bid & 7) * 64 + (bid >> 3);     // 512 blocks, 8 XCDs, bijective
  int mt = swz & 31, nt = swz >> 5;
  int tid = threadIdx.x;
  int w = tid >> 6, lane = tid & 63;
  int wm = w >> 2, wn = w & 3;               // 2 x 4 wave grid, 128x64 each
  int lr = lane & 15, lk = lane >> 4;
  size_t bm = (size_t)mt * 256, bn = (size_t)nt * 256;
  const uint8_t* Ab = Aq + (bm << 12);
  const uint8_t* Bb = Bq + (bn << 12);

  f32x4 acc[8][4] = {};
  lx2 aE0[4], aE1[4], aO0[4], aO1[4], b0[4], b1[4];  // [unit]; 0=grp2t,1=grp2t+1

  // staging: 1 DMA/wave covers one 16-row unit (lane l -> row l&15, chunk l>>4)
  auto STAGE_A = [&](int h, int tile, int buf) {
    gload_lds16(Ab + ((size_t)(h * 128 + w * 16 + lr) << 12) + tile * 64 + lk * 16,
                &smq[buf][0][h][w * 1024]);
  };
  auto STAGE_B = [&](int h, int tile, int buf) {
    gload_lds16(Bb + ((size_t)(h * 128 + w * 16 + lr) << 12) + tile * 64 + lk * 16,
                &smq[buf][1][h][w * 1024]);
  };

  // linear read bases; buf1 = +32768
  uint32_t smb = (uint32_t)(uintptr_t)
      (__attribute__((address_space(3))) uint8_t*)&smq[0][0][0][0];
  uint32_t aA = smb + wm * 8192 + lane * 16;
  uint32_t aB = smb + 16384 + (wn >> 1) * 8192 + (wn & 1) * 4096 + lane * 16;

  // prologue: stage k-groups 0 (buf0) and 1 (buf1); land them for ALL waves.
  STAGE_A(0, 0, 0); STAGE_A(1, 0, 0); STAGE_B(0, 0, 0); STAGE_B(1, 0, 0);
  STAGE_A(0, 1, 1); STAGE_A(1, 1, 1); STAGE_B(0, 1, 1); STAGE_B(1, 1, 1);
  VMC(0);
  BAR();

  for (int tt = 0; tt < NT2; tt++) {
    int s0 = (2 * tt + 2 > 62) ? 62 : 2 * tt + 2;   // clamp: benign re-stage,
    int s1 = (2 * tt + 3 > 63) ? 63 : 2 * tt + 3;   // keeps vmcnt FIFO uniform

    // ---- reads: aE (8), b01 (4), b23 (4) ----
    DSR128(aE0[0], aA, "0");    DSR128(aE1[0], aA, "32768");
    DSR128(aE0[1], aA, "1024"); DSR128(aE1[1], aA, "33792");
    DSR128(aE0[2], aA, "2048"); DSR128(aE1[2], aA, "34816");
    DSR128(aE0[3], aA, "3072"); DSR128(aE1[3], aA, "35840");
    DSR128(b0[0], aB, "0");     DSR128(b1[0], aB, "32768");
    DSR128(b0[1], aB, "1024");  DSR128(b1[1], aB, "33792");
    DSR128(b0[2], aB, "2048");  DSR128(b1[2], aB, "34816");
    DSR128(b0[3], aB, "3072");  DSR128(b1[3], aB, "35840");

    // ---- ph0: E x b01 (32 MFMA) ----
    LGKM(4);                        // aE + b01 done (b23 may lag)
    __builtin_amdgcn_s_setprio(1);
#pragma unroll
    for (int u = 0; u < 4; u++) {
      FMP(acc[u][0], aE0[u], b0[0]); FMP(acc[u][0], aE1[u], b1[0]);
      FMP(acc[u][1], aE0[u], b0[1]); FMP(acc[u][1], aE1[u], b1[1]);
    }
    __builtin_amdgcn_s_setprio(0);

    // ---- ph1: E x b23 (32 MFMA); mid-reads aO (8) ----
    LGKM(0);                        // b23 done
    __builtin_amdgcn_s_setprio(1);
    FMP(acc[0][2], aE0[0], b0[2]); FMP(acc[0][2], aE1[0], b1[2]);
    FMP(acc[0][3], aE0[0], b0[3]); FMP(acc[0][3], aE1[0], b1[3]);
    SGB();
    DSR128(aO0[0], aA, "4096"); DSR128(aO1[0], aA, "36864");
    DSR128(aO0[1], aA, "5120"); DSR128(aO1[1], aA, "37888");
    DSR128(aO0[2], aA, "6144"); DSR128(aO1[2], aA, "38912");
    DSR128(aO0[3], aA, "7168"); DSR128(aO1[3], aA, "39936");
    SGB();
#pragma unroll
    for (int u = 1; u < 4; u++) {
      FMP(acc[u][2], aE0[u], b0[2]); FMP(acc[u][2], aE1[u], b1[2]);
      FMP(acc[u][3], aE0[u], b0[3]); FMP(acc[u][3], aE1[u], b1[3]);
    }
    __builtin_amdgcn_s_setprio(0);

    // ---- ph2: O x b01 (32 MFMA); then BAR + stages ----
    LGKM(0);                        // aO done -> ALL this wave's reads done
    __builtin_amdgcn_s_setprio(1);
#pragma unroll
    for (int u = 0; u < 4; u++) {
      FMP(acc[4 + u][0], aO0[u], b0[0]); FMP(acc[4 + u][0], aO1[u], b1[0]);
      FMP(acc[4 + u][1], aO0[u], b0[1]); FMP(acc[4 + u][1], aO1[u], b1[1]);
    }
    __builtin_amdgcn_s_setprio(0);
    BAR();                          // every wave past LGKM(0) -> overwrite safe
    STAGE_A(0, s0, 0); STAGE_A(1, s0, 0); STAGE_B(0, s0, 0); STAGE_B(1, s0, 0);
    STAGE_A(0, s1, 1); STAGE_A(1, s1, 1); STAGE_B(0, s1, 1); STAGE_B(1, s1, 1);

    // ---- ph3: O x b23 (32 MFMA); drain DMA; BAR ----
    __builtin_amdgcn_s_setprio(1);
#pragma unroll
    for (int u = 0; u < 4; u++) {
      FMP(acc[4 + u][2], aO0[u], b0[2]); FMP(acc[4 + u][2], aO1[u], b1[2]);
      FMP(acc[4 + u][3], aO0[u], b0[3]); FMP(acc[4 + u][3], aO1[u], b1[3]);
    }
    __builtin_amdgcn_s_setprio(0);
    VMC(0);                         // this wave's 8 DMAs landed
    BAR();                          // ...mutual -> next iter reads safe
  }
  VMC(0);
  LGKM(0);

  // epilogue: per-row sum of squares over this wave's 64 cols
  // C frag: col = cb*16 + lr, row = rb*16 + lk*4 + reg
#pragma unroll
  for (int rb = 0; rb < 8; rb++) {
#pragma unroll
    for (int reg = 0; reg < 4; reg++) {
      float s = 0.f;
#pragma unroll
      for (int cb = 0; cb < 4; cb++) { float v = acc[rb][cb][reg]; s += v * v; }
      s += __shfl_xor(s, 1);
      s += __shfl_xor(s, 2);
      s += __shfl_xor(s, 4);
      s += __shfl_xor(s, 8);
      if (lr == 0) {
        int row = (int)bm + wm * 128 + rb * 16 + lk * 4 + reg;
        partial[(size_t)(nt * 4 + wn) * B_DIM + row] = s;
      }
    }
  }
}

// -------- finish: sum 64 partials, sqrt, undo x64 weight scale ----------
__global__ void k_finish(const float* __restrict__ partial, float* __restrict__ out) {
  int b = blockIdx.x * 256 + threadIdx.x;
  float s = 0.f;
#pragma unroll
  for (int i = 0; i < 64; i++) s += partial[(size_t)i * B_DIM + b];
  out[b] = sqrtf(s) * 0.015625f;
}

extern "C" void kernel_launch(void* const* d_in, const int* in_sizes, int n_in,
                              void* d_out, int out_size, void* d_ws, size_t ws_size,
                              hipStream_t stream) {
  const float* x  = (const float*)d_in[0];
  const float* hw = (const float*)d_in[1];
  float* out = (float*)d_out;
  char* ws = (char*)d_ws;
  uint8_t* xq = (uint8_t*)ws;                                     // 32 MB
  uint8_t* wq = (uint8_t*)(ws + (size_t)B_DIM * K_DIM);           // 16 MB
  float* partial = (float*)(ws + (size_t)B_DIM * K_DIM
                               + (size_t)K_DIM * N_DIM);          // 2 MB
  long long R[3];
  mt_randint3(1367u, R);

  k_prep<<<8192 + 16384, 256, 0, stream>>>(x, xq, hw, wq, R[0], R[1], R[2]);
  k_gemm<<<(B_DIM / 256) * (N_DIM / 256), 512, 0, stream>>>(xq, wq, partial);
  k_finish<<<B_DIM / 256, 256, 0, stream>>>(partial, out);
}

// Round 16
// 225.091 us; speedup vs baseline: 1.3665x; 1.3665x over previous
//
#include <hip/hip_runtime.h>
#include <stdint.h>
#include <math.h>

typedef __bf16 bf16;
typedef float f32x4 __attribute__((ext_vector_type(4)));
typedef long  lx2  __attribute__((ext_vector_type(2)));

#define B_DIM 8192
#define K_DIM 4096
#define N_DIM 4096
#define MEM_H 1048576
#define HMOD  1047552   // MEM_H - 32*32
#define NT    (K_DIM / 64)

// ---------------- host-side numpy legacy RNG replication ----------------
static void mt_randint3(uint32_t seed, long long R[3]) {
  uint32_t mt[624];
  mt[0] = seed;
  for (int i = 1; i < 624; i++)
    mt[i] = 1812433253u * (mt[i - 1] ^ (mt[i - 1] >> 30)) + (uint32_t)i;
  int pos = 624;
  auto next32 = [&]() -> uint32_t {
    if (pos >= 624) {
      for (int i = 0; i < 624; i++) {
        uint32_t y = (mt[i] & 0x80000000u) | (mt[(i + 1) % 624] & 0x7fffffffu);
        uint32_t v = mt[(i + 397) % 624] ^ (y >> 1);
        if (y & 1u) v ^= 0x9908b0dfu;
        mt[i] = v;
      }
      pos = 0;
    }
    uint32_t y = mt[pos++];
    y ^= y >> 11;
    y ^= (y << 7) & 0x9d2c5680u;
    y ^= (y << 15) & 0xefc60000u;
    y ^= y >> 18;
    return y;
  };
  for (int j = 0; j < 3; j++) {
    uint32_t v;
    do { v = next32() & 0x7fffffffu; } while (v > 0x7ffffffdu);
    R[j] = 1LL + (long long)v;
  }
}

// ---------------- f32 -> OCP e4m3fn, RTN-even, with subnormals ----------
__device__ __forceinline__ uint32_t f2e4m3(float f) {
  uint32_t u = __float_as_uint(f);
  uint32_t s = (u >> 24) & 0x80u;
  float a = fabsf(f);
  uint32_t b;
  if (a < 0.015625f) {
    b = (uint32_t)(int)rintf(a * 512.0f);        // 0..8 ; 8 == 2^-6 normal
  } else {
    uint32_t au = __float_as_uint(a);
    au += 0x7FFFFu + ((au >> 20) & 1u);          // round mantissa to 3 bits
    int E = (int)(au >> 23) - 127;
    if (E > 8) b = 0x7Eu;                        // saturate to 448
    else b = (uint32_t)(((E + 7) << 3) | ((au >> 20) & 7u));
  }
  return b | s;
}

// -------- fused pre-pass: quantize x AND build W^T, PACKED layout -------
// Packed 64B k-group: 16B chunk c = [k 8c..8c+7 | k 32+8c..32+8c+7].
__global__ void k_prep(const float* __restrict__ x, uint8_t* __restrict__ xq,
                       const float* __restrict__ hw, uint8_t* __restrict__ wq,
                       long long R1, long long R2, long long R3) {
  if (blockIdx.x < 8192) {
    int id = blockIdx.x * 256 + threadIdx.x;     // one packed 16B chunk
    int row = id >> 8, q = id & 255;
    int g = q >> 2, c = q & 3;
    const float* base = x + (size_t)row * 4096 + g * 64 + c * 8;
    f32x4 v0 = *(const f32x4*)(base);
    f32x4 v1 = *(const f32x4*)(base + 4);
    f32x4 v2 = *(const f32x4*)(base + 32);
    f32x4 v3 = *(const f32x4*)(base + 36);
    uint32_t r0 = f2e4m3(v0[0]) | (f2e4m3(v0[1]) << 8) |
                  (f2e4m3(v0[2]) << 16) | (f2e4m3(v0[3]) << 24);
    uint32_t r1 = f2e4m3(v1[0]) | (f2e4m3(v1[1]) << 8) |
                  (f2e4m3(v1[2]) << 16) | (f2e4m3(v1[3]) << 24);
    uint32_t r2 = f2e4m3(v2[0]) | (f2e4m3(v2[1]) << 8) |
                  (f2e4m3(v2[2]) << 16) | (f2e4m3(v2[3]) << 24);
    uint32_t r3 = f2e4m3(v3[0]) | (f2e4m3(v3[1]) << 8) |
                  (f2e4m3(v3[2]) << 16) | (f2e4m3(v3[3]) << 24);
    ((uint4*)xq)[id] = make_uint4(r0, r1, r2, r3);
  } else {
    int tile = blockIdx.x - 8192;
    int kb = tile & 127, nb = tile >> 7;
    long long v = (long long)kb * R3 + (long long)nb * R2 + R1;
    int start = (int)((v % 2147483647LL) % (long long)HMOD);
    const float* src = hw + start;
    int t = threadIdx.x;
    int nl = t >> 3, k4 = t & 7;
    uint32_t b = 0;
#pragma unroll
    for (int j = 0; j < 4; j++)
      b |= f2e4m3(src[(k4 * 4 + j) * 32 + nl] * 64.0f) << (8 * j);
    size_t off = (size_t)(nb * 32 + nl) * 4096 + (kb >> 1) * 64 +
                 (k4 >> 1) * 16 + (kb & 1) * 8 + (k4 & 1) * 4;
    *(uint32_t*)(wq + off) = b;
  }
}

// ---- 256x256x64 fp8 GEMM: R13 structure, barriers thinned 4->2/tile ----
// Kept verbatim from R13: packed-linear LDS (conflict-free b128 reads),
// counted VMC(2) at ph2-end (deep prefetch, distance-2 staging), counted
// lgkm phase gates, reads-inside-MFMA. Removed: end-ph0 and end-ph3
// barriers — redundant per the dependency audit:
//   STAGE_B@ph2 needs bg01/bg23(cur) reads chip-wide-done -> ph1-top
//   LGKM(0) + end-ph1 BAR covers both. STAGE_A@ph3 needs afE/afO(cur)
//   reads -> ph0/ph2-top LGKM(0) + end-ph2 BAR. DMA landing for ph3-mid
//   reads of nxt -> VMC(2)@ph2-end drains all of t+1 (FIFO verified).
__device__ __forceinline__ void gload_lds16(const void* g, void* l) {
  __builtin_amdgcn_global_load_lds(
      (const __attribute__((address_space(1))) void*)g,
      (__attribute__((address_space(3))) void*)l, 16, 0, 0);
}

#define SGB() __builtin_amdgcn_sched_barrier(0)
#define VMC(n)  do { SGB(); asm volatile("s_waitcnt vmcnt(" #n ")"); SGB(); } while (0)
#define LGKM(n) do { SGB(); asm volatile("s_waitcnt lgkmcnt(" #n ")"); SGB(); } while (0)
#define BAR() __builtin_amdgcn_s_barrier()
#define DSR128(dst, base, off) \
  asm volatile("ds_read_b128 %0, %1 offset:" off : "=&v"(dst) : "v"(base))

#define FM(RH, R4, CB, KS, AF)                                                 \
  acc[(RH)*4 + (R4)][CB] = __builtin_amdgcn_mfma_f32_16x16x32_fp8_fp8(         \
      AF[R4][KS], bg[CB][KS], acc[(RH)*4 + (R4)][CB], 0, 0, 0)
#define FM4(RH, CB, KS, AF) do {                                               \
  FM(RH, 0, CB, KS, AF); FM(RH, 1, CB, KS, AF);                                \
  FM(RH, 2, CB, KS, AF); FM(RH, 3, CB, KS, AF); } while (0)

__global__ __launch_bounds__(512, 2) void k_gemm(const uint8_t* __restrict__ Aq,
                                                 const uint8_t* __restrict__ Bq,
                                                 float* __restrict__ partial) {
  // [buf][op 0=A 1=B][half][8 units x 1KB] : 64 KiB
  __shared__ uint8_t smq[2][2][2][128 * 64];
  int bid = blockIdx.x;
  int swz = (bid & 7) * 64 + (bid >> 3);     // 512 blocks, 8 XCDs, bijective
  int mt = swz & 31, nt = swz >> 5;
  int tid = threadIdx.x;
  int w = tid >> 6, lane = tid & 63;
  int wm = w >> 2, wn = w & 3;               // 2 x 4 wave grid, 128x64 each
  int lr = lane & 15, lk = lane >> 4;
  size_t bm = (size_t)mt * 256, bn = (size_t)nt * 256;
  const uint8_t* Ab = Aq + (bm << 12);
  const uint8_t* Bb = Bq + (bn << 12);

  f32x4 acc[8][4] = {};
  lx2 afE[4], afO[4], bg[4];                 // [unit]; [0]=ks0, [1]=ks1

  // staging: 1 DMA/wave covers one 16-row unit (lane l -> row l&15, chunk l>>4)
  auto STAGE_A = [&](int h, int tt, int buf) {
    gload_lds16(Ab + ((size_t)(h * 128 + w * 16 + lr) << 12) + tt * 64 + lk * 16,
                &smq[buf][0][h][w * 1024]);
  };
  auto STAGE_B = [&](int h, int tt, int buf) {
    gload_lds16(Bb + ((size_t)(h * 128 + w * 16 + lr) << 12) + tt * 64 + lk * 16,
                &smq[buf][1][h][w * 1024]);
  };

  // read bases (buf0): perfectly linear base + lane*16
  uint32_t smb = (uint32_t)(uintptr_t)
      (__attribute__((address_space(3))) uint8_t*)&smq[0][0][0][0];
  uint32_t aA = smb + wm * 8192 + lane * 16;
  uint32_t aB = smb + 16384 + (wn >> 1) * 8192 + (wn & 1) * 4096 + lane * 16;

  // prologue: stage t0 (4 DMA) + t1 (4); VMC(4)+BAR lands t0 for ALL waves;
  // pre-read afE(t0) + bg01(t0).
  STAGE_A(0, 0, 0); STAGE_A(1, 0, 0);
  STAGE_B(0, 0, 0); STAGE_B(1, 0, 0);
  STAGE_A(0, 1, 1); STAGE_A(1, 1, 1);
  STAGE_B(0, 1, 1); STAGE_B(1, 1, 1);
  VMC(4);
  BAR();
  DSR128(afE[0], aA, "0");    DSR128(afE[1], aA, "1024");
  DSR128(afE[2], aA, "2048"); DSR128(afE[3], aA, "3072");
  DSR128(bg[0], aB, "0");     DSR128(bg[1], aB, "1024");

  for (int t = 0; t < NT; t++) {
    int t2 = (t + 2 < NT) ? t + 2 : NT - 1;  // clamp keeps vmcnt FIFO uniform
    int cur = t & 1;
    uint32_t bsel = (uint32_t)cur << 15;
    uint32_t Ac = aA + bsel, Bc = aB + bsel;
    uint32_t An = Ac ^ 32768u, Bn = Bc ^ 32768u;

    // ---- ph0: MM(afE,bg01); mid-reads bg23(cur) ----  [no end barrier]
    LGKM(0);                       // afE(t)+bg01(t) from ph3-mid(t-1)
    __builtin_amdgcn_s_setprio(1);
    FM4(0, 0, 0, afE);
    SGB();
    DSR128(bg[2], Bc, "2048"); DSR128(bg[3], Bc, "3072");
    SGB();
    FM4(0, 1, 0, afE); FM4(0, 0, 1, afE); FM4(0, 1, 1, afE);
    __builtin_amdgcn_s_setprio(0);

    // ---- ph1: MM(afE,bg23); mid-reads afO(cur); BAR#1 ----
    LGKM(0);                       // bg23(t)
    __builtin_amdgcn_s_setprio(1);
    FM4(0, 2, 0, afE);
    SGB();
    DSR128(afO[0], Ac, "4096"); DSR128(afO[1], Ac, "5120");
    DSR128(afO[2], Ac, "6144"); DSR128(afO[3], Ac, "7168");
    SGB();
    FM4(0, 3, 0, afE); FM4(0, 2, 1, afE); FM4(0, 3, 1, afE);
    __builtin_amdgcn_s_setprio(0);
    BAR();                         // all waves past ph1-top LGKM(0):
                                   // B(cur) fully read chip-wide

    // ---- ph2: MM(afO,bg01); stage B(t+2)->cur; VMC(2); BAR#2 ----
    LGKM(0);                       // afO(t)
    __builtin_amdgcn_s_setprio(1);
    FM4(1, 0, 0, afO); FM4(1, 1, 0, afO);
    FM4(1, 0, 1, afO); FM4(1, 1, 1, afO);
    __builtin_amdgcn_s_setprio(0);
    STAGE_B(0, t2, cur); STAGE_B(1, t2, cur);
    VMC(2);                        // drains B(t+1),A(t+1) for THIS wave
    BAR();                         // mutual: t+1 landed; A(cur) fully read

    // ---- ph3: MM(afO,bg23); mid-reads afE+bg01(nxt); stage A(t+2) ----
    __builtin_amdgcn_s_setprio(1); // no lgkm: afO/bg23 already waited
    FM4(1, 2, 0, afO);
    SGB();
    DSR128(afE[0], An, "0");    DSR128(afE[1], An, "1024");
    DSR128(afE[2], An, "2048"); DSR128(afE[3], An, "3072");
    DSR128(bg[0], Bn, "0");     DSR128(bg[1], Bn, "1024");
    SGB();
    FM4(1, 3, 0, afO); FM4(1, 2, 1, afO); FM4(1, 3, 1, afO);
    __builtin_amdgcn_s_setprio(0);
    STAGE_A(0, t2, cur); STAGE_A(1, t2, cur);   // [no end barrier]
  }
  VMC(0);
  LGKM(0);   // drain tail DMA + dangling reads before epilogue

  // epilogue: per-row sum of squares over this wave's 64 cols
  // C frag: col = cb*16 + (lane&15), row = rb*16 + (lane>>4)*4 + reg
#pragma unroll
  for (int rb = 0; rb < 8; rb++) {
#pragma unroll
    for (int reg = 0; reg < 4; reg++) {
      float s = 0.f;
#pragma unroll
      for (int cb = 0; cb < 4; cb++) { float v = acc[rb][cb][reg]; s += v * v; }
      s += __shfl_xor(s, 1);
      s += __shfl_xor(s, 2);
      s += __shfl_xor(s, 4);
      s += __shfl_xor(s, 8);
      if (lr == 0) {
        int row = (int)bm + wm * 128 + rb * 16 + lk * 4 + reg;
        partial[(size_t)(nt * 4 + wn) * B_DIM + row] = s;
      }
    }
  }
}

// -------- finish: sum 64 partials, sqrt, undo x64 weight scale ----------
__global__ void k_finish(const float* __restrict__ partial, float* __restrict__ out) {
  int b = blockIdx.x * 256 + threadIdx.x;
  float s = 0.f;
#pragma unroll
  for (int i = 0; i < 64; i++) s += partial[(size_t)i * B_DIM + b];
  out[b] = sqrtf(s) * 0.015625f;
}

extern "C" void kernel_launch(void* const* d_in, const int* in_sizes, int n_in,
                              void* d_out, int out_size, void* d_ws, size_t ws_size,
                              hipStream_t stream) {
  const float* x  = (const float*)d_in[0];
  const float* hw = (const float*)d_in[1];
  float* out = (float*)d_out;
  char* ws = (char*)d_ws;
  uint8_t* xq = (uint8_t*)ws;                                     // 32 MB
  uint8_t* wq = (uint8_t*)(ws + (size_t)B_DIM * K_DIM);           // 16 MB
  float* partial = (float*)(ws + (size_t)B_DIM * K_DIM
                               + (size_t)K_DIM * N_DIM);          // 2 MB
  long long R[3];
  mt_randint3(1367u, R);

  k_prep<<<8192 + 16384, 256, 0, stream>>>(x, xq, hw, wq, R[0], R[1], R[2]);
  k_gemm<<<(B_DIM / 256) * (N_DIM / 256), 512, 0, stream>>>(xq, wq, partial);
  k_finish<<<B_DIM / 256, 256, 0, stream>>>(partial, out);
}